// Round 7
// baseline (746.354 us; speedup 1.0000x reference)
//
#include <hip/hip_runtime.h>

#define T_TOK 8192
#define DDIM 1024
#define GH1 512
#define GH2 256
#define NEXP 8
#define HDIM 2048

typedef __attribute__((ext_vector_type(8))) short short8;
typedef __attribute__((ext_vector_type(4))) float f32x4;

__device__ __forceinline__ unsigned short f2bf(float f) {
    unsigned int u = __float_as_uint(f);
    u += 0x7fffu + ((u >> 16) & 1u);
    return (unsigned short)(u >> 16);
}
__device__ __forceinline__ float bf2f(unsigned short h) {
    return __uint_as_float(((unsigned int)h) << 16);
}

__device__ __forceinline__ void async16(const void* g, void* l) {
#if __has_builtin(__builtin_amdgcn_global_load_lds)
    __builtin_amdgcn_global_load_lds((const __attribute__((address_space(1))) void*)g,
                                     (__attribute__((address_space(3))) void*)l, 16, 0, 0);
#else
    *(uint4*)l = *(const uint4*)g;
#endif
}

// ---------------- fp32 -> bf16 elementwise (x -> xb) ----------------
__global__ __launch_bounds__(256)
void f2b_kernel(const float* __restrict__ in, unsigned short* __restrict__ out)
{
    size_t i = ((size_t)blockIdx.x * 256 + threadIdx.x) * 8;
    float4 a = *(const float4*)(in + i);
    float4 b = *(const float4*)(in + i + 4);
    uint4 r;
    r.x = (unsigned)f2bf(a.x) | ((unsigned)f2bf(a.y) << 16);
    r.y = (unsigned)f2bf(a.z) | ((unsigned)f2bf(a.w) << 16);
    r.z = (unsigned)f2bf(b.x) | ((unsigned)f2bf(b.y) << 16);
    r.w = (unsigned)f2bf(b.z) | ((unsigned)f2bf(b.w) << 16);
    *(uint4*)(out + i) = r;
}

// ---------- fp32 [z][R][C] -> bf16 [z][C][R] tiled transpose ----------
__global__ __launch_bounds__(256)
void transpose_f2b(const float* __restrict__ in, unsigned short* __restrict__ out,
                   int R, int C, int tilesC, int ntile)
{
    int bid = blockIdx.x;
    int z = bid / ntile;
    int r = bid - z * ntile;
    int tr = r / tilesC, tc = r - tr * tilesC;
    const float* ib = in + (size_t)z * R * C;
    unsigned short* ob = out + (size_t)z * R * C;
    __shared__ float lds[32][33];
    int t = threadIdx.x;
    int i = t >> 3, j4 = (t & 7) << 2;
    float4 v = *(const float4*)(ib + (size_t)(tr * 32 + i) * C + tc * 32 + j4);
    lds[i][j4 + 0] = v.x;
    lds[i][j4 + 1] = v.y;
    lds[i][j4 + 2] = v.z;
    lds[i][j4 + 3] = v.w;
    __syncthreads();
    ushort4 o;
    o.x = f2bf(lds[j4 + 0][i]);
    o.y = f2bf(lds[j4 + 1][i]);
    o.z = f2bf(lds[j4 + 2][i]);
    o.w = f2bf(lds[j4 + 3][i]);
    *(ushort4*)(ob + (size_t)(tc * 32 + i) * R + tr * 32 + j4) = o;
}

// ---------------- fp32 SGEMM + bias + relu (gating L1/L2) ----------------
// C[M][N] = relu(A[M][K] @ B[K][N] + bias). Tile 128x128, 256 thr, 8x8/thr.
__global__ __launch_bounds__(256)
void sgemm_relu(const float* __restrict__ A, const float* __restrict__ B,
                const float* __restrict__ bias, float* __restrict__ C,
                int N, int Kd, int nbn)
{
    int bid = blockIdx.x;
    int bm = bid / nbn, bn = bid - bm * nbn;
    __shared__ float As[16 * 128];   // [kk][row]
    __shared__ float Bs[16 * 128];   // [kk][col]
    int t = threadIdx.x;
    int tx = t & 15, ty = t >> 4;
    float acc[8][8];
#pragma unroll
    for (int i = 0; i < 8; ++i)
#pragma unroll
        for (int j = 0; j < 8; ++j) acc[i][j] = 0.f;

    for (int k0 = 0; k0 < Kd; k0 += 16) {
        __syncthreads();
#pragma unroll
        for (int c = 0; c < 2; ++c) {
            int idx = t + c * 256;
            int row = idx >> 2, kk = (idx & 3) << 2;
            float4 v = *(const float4*)(A + (size_t)(bm * 128 + row) * Kd + k0 + kk);
            As[(kk + 0) * 128 + row] = v.x;
            As[(kk + 1) * 128 + row] = v.y;
            As[(kk + 2) * 128 + row] = v.z;
            As[(kk + 3) * 128 + row] = v.w;
            int kk2 = idx >> 5, n2 = (idx & 31) << 2;
            *(float4*)&Bs[kk2 * 128 + n2] =
                *(const float4*)(B + (size_t)(k0 + kk2) * N + bn * 128 + n2);
        }
        __syncthreads();
#pragma unroll
        for (int kk = 0; kk < 16; ++kk) {
            float a[8], b[8];
            *(float4*)&a[0] = *(const float4*)&As[kk * 128 + ty * 8];
            *(float4*)&a[4] = *(const float4*)&As[kk * 128 + ty * 8 + 4];
            *(float4*)&b[0] = *(const float4*)&Bs[kk * 128 + tx * 8];
            *(float4*)&b[4] = *(const float4*)&Bs[kk * 128 + tx * 8 + 4];
#pragma unroll
            for (int i = 0; i < 8; ++i)
#pragma unroll
                for (int j = 0; j < 8; ++j)
                    acc[i][j] = fmaf(a[i], b[j], acc[i][j]);
        }
    }
#pragma unroll
    for (int i = 0; i < 8; ++i) {
        int row = bm * 128 + ty * 8 + i;
#pragma unroll
        for (int j = 0; j < 8; ++j) {
            int col = bn * 128 + tx * 8 + j;
            float v = acc[i][j] + bias[col];
            C[(size_t)row * N + col] = v > 0.f ? v : 0.f;
        }
    }
}

// ------------- gating L3 + type bias + softmax + top2 (per token) -------------
__global__ __launch_bounds__(256)
void gate_tail(const float* __restrict__ h2, const int* __restrict__ ftyp,
               const float* __restrict__ gw3, const float* __restrict__ gb3,
               const float* __restrict__ temb, const float* __restrict__ tw,
               const float* __restrict__ tb,
               int* __restrict__ eidx, float* __restrict__ ewt)
{
    __shared__ float sw3[GH2 * NEXP];
    __shared__ float stw[128 * NEXP];
    __shared__ float ste[3 * 128];
    int t = threadIdx.x;
    for (int i = t; i < GH2 * NEXP; i += 256) sw3[i] = gw3[i];
    for (int i = t; i < 128 * NEXP; i += 256) stw[i] = tw[i];
    for (int i = t; i < 3 * 128; i += 256) ste[i] = temb[i];
    __syncthreads();
    int tok = blockIdx.x * 256 + t;
    float lg[NEXP];
#pragma unroll
    for (int e = 0; e < NEXP; ++e) lg[e] = gb3[e] + tb[e];
    const float* hrow = h2 + (size_t)tok * GH2;
    for (int k = 0; k < GH2; k += 4) {
        float4 hv = *(const float4*)(hrow + k);
        float hvv[4] = {hv.x, hv.y, hv.z, hv.w};
#pragma unroll
        for (int j = 0; j < 4; ++j) {
            float v = hvv[j];
#pragma unroll
            for (int e = 0; e < NEXP; ++e)
                lg[e] = fmaf(v, sw3[(k + j) * NEXP + e], lg[e]);
        }
    }
    int ft = ftyp[tok];
    const float* te = ste + ft * 128;
    for (int k = 0; k < 128; k += 4) {
#pragma unroll
        for (int j = 0; j < 4; ++j) {
            float v = te[k + j];
#pragma unroll
            for (int e = 0; e < NEXP; ++e)
                lg[e] = fmaf(v, stw[(k + j) * NEXP + e], lg[e]);
        }
    }
    // top-2 on logits (softmax is monotone); ties -> lower index (matches lax.top_k)
    int a0 = 0; float b0 = lg[0];
#pragma unroll
    for (int e = 1; e < NEXP; ++e) if (lg[e] > b0) { b0 = lg[e]; a0 = e; }
    int a1 = -1; float b1 = -3.4e38f;
#pragma unroll
    for (int e = 0; e < NEXP; ++e) if (e != a0 && lg[e] > b1) { b1 = lg[e]; a1 = e; }
    // renormalized top-2 softmax weights == softmax over the two selected logits
    float w0 = 1.f / (1.f + expf(b1 - b0));
    eidx[tok * 2 + 0] = a0;
    eidx[tok * 2 + 1] = a1;
    ewt[tok * 2 + 0] = w0;
    ewt[tok * 2 + 1] = 1.f - w0;
}

// ---------------- routing: per-expert index lists ----------------
__global__ __launch_bounds__(256)
void route_kernel(const int* __restrict__ eidx, int* __restrict__ cnt,
                  int* __restrict__ entries)
{
    int tok = blockIdx.x * 256 + threadIdx.x;
#pragma unroll
    for (int k = 0; k < 2; ++k) {
        int e = eidx[tok * 2 + k];
        int p = atomicAdd(&cnt[e], 1);
        entries[e * T_TOK + p] = (tok << 1) | k;
    }
}

// ---------------- bf16 MFMA GEMM, 128x128 tile, BK=32 ----------------
// GATHER=1: expert GEMM. A rows gathered via entries[e]; writes bf16 into
//           Y0/Y1 per (token,slot) with eb bias. Block mapping is
//           XCD-aligned: e = bid % 8, so all blocks of expert e land on
//           XCD e (HW round-robin bid%8->XCD) and e's 4MB B-panel fits
//           that XCD's 4MB L2. Bijective since grid = 8*nbm*nbn.
// GATHER=0: plain GEMM, fp32 out + bias.
template<int GATHER>
__global__ __launch_bounds__(256)
void bgemm(const unsigned short* __restrict__ A, const unsigned short* __restrict__ BT,
           const float* __restrict__ bias, float* __restrict__ Cf,
           unsigned short* __restrict__ Y0, unsigned short* __restrict__ Y1,
           const int* __restrict__ entries, const int* __restrict__ cnt,
           int N, int Kd, int nbm, int nbn)
{
    int bid = blockIdx.x;
    int e = 0, bm, bn, cntE = 0;
    const unsigned short* Bt = BT;
    const float* bs = bias;
    if (GATHER) {
        e = bid & (NEXP - 1);          // expert == XCD (round-robin dispatch)
        int r = bid >> 3;              // [0, nbm*nbn)
        bm = r / nbn; bn = r - bm * nbn;
        cntE = cnt[e];
        if (bm * 128 >= cntE) return;
        Bt = BT + (size_t)e * HDIM * DDIM;
        bs = bias + e * HDIM;
    } else {
        bm = bid / nbn; bn = bid - bm * nbn;
    }

    __shared__ __align__(16) unsigned short As[128 * 32];
    __shared__ __align__(16) unsigned short Bs[128 * 32];
    __shared__ int rowtok[128];

    int t = threadIdx.x;
    if (GATHER) {
        if (t < 128) {
            int idx = bm * 128 + t;
            rowtok[t] = entries[(size_t)e * T_TOK + bm * 128 + ((idx < cntE) ? t : 0)];
        }
        __syncthreads();
    }

    int arow0 = t >> 2;
    int kkA = (t & 3) << 3;
    const unsigned short *asrc0, *asrc1;
    if (GATHER) {
        asrc0 = A + (size_t)(rowtok[arow0] >> 1) * Kd + kkA;
        asrc1 = A + (size_t)(rowtok[arow0 + 64] >> 1) * Kd + kkA;
    } else {
        asrc0 = A + (size_t)(bm * 128 + arow0) * Kd + kkA;
        asrc1 = A + (size_t)(bm * 128 + arow0 + 64) * Kd + kkA;
    }
    const unsigned short* bsrc0 = Bt + (size_t)(bn * 128 + arow0) * Kd + kkA;
    const unsigned short* bsrc1 = Bt + (size_t)(bn * 128 + arow0 + 64) * Kd + kkA;
    unsigned short* adst0 = As + t * 8;
    unsigned short* adst1 = As + t * 8 + 2048;
    unsigned short* bdst0 = Bs + t * 8;
    unsigned short* bdst1 = Bs + t * 8 + 2048;

    int lane = t & 63, wave = t >> 6;
    int wr = (wave >> 1) * 64, wc = (wave & 1) * 64;
    int l15 = lane & 15, lhi = lane >> 4;

    f32x4 zero = {0.f, 0.f, 0.f, 0.f};
    f32x4 acc[4][4];
#pragma unroll
    for (int m = 0; m < 4; ++m)
#pragma unroll
        for (int n = 0; n < 4; ++n) acc[m][n] = zero;

    for (int k0 = 0; k0 < Kd; k0 += 32) {
        __syncthreads();
        async16(asrc0 + k0, adst0);
        async16(asrc1 + k0, adst1);
        async16(bsrc0 + k0, bdst0);
        async16(bsrc1 + k0, bdst1);
        __syncthreads();
        short8 af[4], bf[4];
#pragma unroll
        for (int m = 0; m < 4; ++m)
            af[m] = *(const short8*)&As[(wr + m * 16 + l15) * 32 + lhi * 8];
#pragma unroll
        for (int n = 0; n < 4; ++n)
            bf[n] = *(const short8*)&Bs[(wc + n * 16 + l15) * 32 + lhi * 8];
#pragma unroll
        for (int m = 0; m < 4; ++m)
#pragma unroll
            for (int n = 0; n < 4; ++n)
                acc[m][n] = __builtin_amdgcn_mfma_f32_16x16x32_bf16(af[m], bf[n], acc[m][n], 0, 0, 0);
    }

    if (GATHER) {
#pragma unroll
        for (int m = 0; m < 4; ++m) {
            int rl = wr + m * 16 + lhi * 4;
#pragma unroll
            for (int q = 0; q < 4; ++q) {
                int gidx = bm * 128 + rl + q;
                if (gidx < cntE) {
                    int ent = rowtok[rl + q];
                    unsigned short* Y = (ent & 1) ? Y1 : Y0;
                    size_t rowoff = (size_t)(ent >> 1) * HDIM;
#pragma unroll
                    for (int n = 0; n < 4; ++n) {
                        int col = bn * 128 + wc + n * 16 + l15;
                        Y[rowoff + col] = f2bf(acc[m][n][q] + bs[col]);
                    }
                }
            }
        }
    } else {
#pragma unroll
        for (int m = 0; m < 4; ++m) {
            int row = bm * 128 + wr + m * 16 + lhi * 4;
#pragma unroll
            for (int n = 0; n < 4; ++n) {
                int col = bn * 128 + wc + n * 16 + l15;
                float bv = bs[col];
#pragma unroll
                for (int q = 0; q < 4; ++q)
                    Cf[(size_t)(row + q) * N + col] = acc[m][n][q] + bv;
            }
        }
    }
}

// ------------- combine: h = relu(w0*Y0 + w1*Y1) -> bf16 Hc -------------
__global__ __launch_bounds__(256)
void combine_kernel(const unsigned short* __restrict__ Y0,
                    const unsigned short* __restrict__ Y1,
                    const float* __restrict__ wts,
                    unsigned short* __restrict__ Hc)
{
    size_t i = (size_t)blockIdx.x * 256 + threadIdx.x;
    size_t base = i * 8;
    int tok = (int)(base >> 11);   // / HDIM
    float w0 = wts[tok * 2], w1 = wts[tok * 2 + 1];
    uint4 a = *(const uint4*)(Y0 + base);
    uint4 b = *(const uint4*)(Y1 + base);
    unsigned int ain[4] = {a.x, a.y, a.z, a.w};
    unsigned int bin[4] = {b.x, b.y, b.z, b.w};
    unsigned int r[4];
#pragma unroll
    for (int q = 0; q < 4; ++q) {
        float v0 = w0 * bf2f((unsigned short)(ain[q] & 0xffff)) +
                   w1 * bf2f((unsigned short)(bin[q] & 0xffff));
        float v1 = w0 * bf2f((unsigned short)(ain[q] >> 16)) +
                   w1 * bf2f((unsigned short)(bin[q] >> 16));
        v0 = v0 > 0.f ? v0 : 0.f;
        v1 = v1 > 0.f ? v1 : 0.f;
        r[q] = (unsigned int)f2bf(v0) | ((unsigned int)f2bf(v1) << 16);
    }
    uint4 o = {r[0], r[1], r[2], r[3]};
    *(uint4*)(Hc + base) = o;
}

// ------------------------------ launch ------------------------------
extern "C" void kernel_launch(void* const* d_in, const int* in_sizes, int n_in,
                              void* d_out, int out_size, void* d_ws, size_t ws_size,
                              hipStream_t stream)
{
    const float* x    = (const float*)d_in[0];
    const int*   ftyp = (const int*)d_in[1];
    const float* gw1  = (const float*)d_in[2];
    const float* gb1  = (const float*)d_in[3];
    const float* gw2  = (const float*)d_in[4];
    const float* gb2  = (const float*)d_in[5];
    const float* gw3  = (const float*)d_in[6];
    const float* gb3  = (const float*)d_in[7];
    const float* temb = (const float*)d_in[8];
    const float* tw   = (const float*)d_in[9];
    const float* tb   = (const float*)d_in[10];
    const float* ew   = (const float*)d_in[11];
    const float* eb   = (const float*)d_in[12];
    const float* ow   = (const float*)d_in[13];
    const float* ob   = (const float*)d_in[14];
    float* out = (float*)d_out;

    char* p = (char*)d_ws;
    auto alloc = [&](size_t bytes) {
        char* r = p;
        p += (bytes + 255) & ~(size_t)255;
        return r;
    };
    unsigned short* xb  = (unsigned short*)alloc((size_t)T_TOK * DDIM * 2);
    float* h1           = (float*)alloc((size_t)T_TOK * GH1 * 4);
    float* h2           = (float*)alloc((size_t)T_TOK * GH2 * 4);
    int* eidx           = (int*)alloc((size_t)T_TOK * 2 * 4);
    float* ewt          = (float*)alloc((size_t)T_TOK * 2 * 4);
    int* cnt            = (int*)alloc(256);
    int* entries        = (int*)alloc((size_t)NEXP * T_TOK * 4);
    unsigned short* ewT = (unsigned short*)alloc((size_t)NEXP * HDIM * DDIM * 2);
    unsigned short* owT = (unsigned short*)alloc((size_t)DDIM * HDIM * 2);
    unsigned short* Y0  = (unsigned short*)alloc((size_t)T_TOK * HDIM * 2);
    unsigned short* Y1  = (unsigned short*)alloc((size_t)T_TOK * HDIM * 2);
    unsigned short* Hc  = (unsigned short*)alloc((size_t)T_TOK * HDIM * 2);

    hipMemsetAsync(cnt, 0, 256, stream);
    f2b_kernel<<<(T_TOK * DDIM / 8) / 256, 256, 0, stream>>>(x, xb);
    // ew [8][1024][2048] -> ewT [8][2048][1024]
    transpose_f2b<<<NEXP * 32 * 64, 256, 0, stream>>>(ew, ewT, DDIM, HDIM, 64, 32 * 64);
    // ow [2048][1024] -> owT [1024][2048]
    transpose_f2b<<<64 * 32, 256, 0, stream>>>(ow, owT, HDIM, DDIM, 32, 64 * 32);

    sgemm_relu<<<64 * 4, 256, 0, stream>>>(x, gw1, gb1, h1, GH1, DDIM, 4);
    sgemm_relu<<<64 * 2, 256, 0, stream>>>(h1, gw2, gb2, h2, GH2, GH1, 2);
    gate_tail<<<T_TOK / 256, 256, 0, stream>>>(h2, ftyp, gw3, gb3, temb, tw, tb, eidx, ewt);
    route_kernel<<<T_TOK / 256, 256, 0, stream>>>(eidx, cnt, entries);

    bgemm<1><<<NEXP * 64 * 16, 256, 0, stream>>>(xb, ewT, eb, nullptr, Y0, Y1,
                                                 entries, cnt, HDIM, DDIM, 64, 16);
    combine_kernel<<<(T_TOK * HDIM / 8) / 256, 256, 0, stream>>>(Y0, Y1, ewt, Hc);
    bgemm<0><<<64 * 8, 256, 0, stream>>>(Hc, owT, ob, out, nullptr, nullptr,
                                         nullptr, nullptr, DDIM, HDIM, 64, 8);
}

// Round 8
// 670.502 us; speedup vs baseline: 1.1131x; 1.1131x over previous
//
#include <hip/hip_runtime.h>

#define T_TOK 8192
#define DDIM 1024
#define GH1 512
#define GH2 256
#define NEXP 8
#define HDIM 2048

typedef __attribute__((ext_vector_type(8))) short short8;
typedef __attribute__((ext_vector_type(4))) float f32x4;

__device__ __forceinline__ unsigned short f2bf(float f) {
    unsigned int u = __float_as_uint(f);
    u += 0x7fffu + ((u >> 16) & 1u);
    return (unsigned short)(u >> 16);
}
__device__ __forceinline__ float bf2f(unsigned short h) {
    return __uint_as_float(((unsigned int)h) << 16);
}

__device__ __forceinline__ void async16(const void* g, void* l) {
#if __has_builtin(__builtin_amdgcn_global_load_lds)
    __builtin_amdgcn_global_load_lds((const __attribute__((address_space(1))) void*)g,
                                     (__attribute__((address_space(3))) void*)l, 16, 0, 0);
#else
    *(uint4*)l = *(const uint4*)g;
#endif
}

// ---------------- fp32 -> bf16 elementwise (x -> xb) ----------------
__global__ __launch_bounds__(256)
void f2b_kernel(const float* __restrict__ in, unsigned short* __restrict__ out)
{
    size_t i = ((size_t)blockIdx.x * 256 + threadIdx.x) * 8;
    float4 a = *(const float4*)(in + i);
    float4 b = *(const float4*)(in + i + 4);
    uint4 r;
    r.x = (unsigned)f2bf(a.x) | ((unsigned)f2bf(a.y) << 16);
    r.y = (unsigned)f2bf(a.z) | ((unsigned)f2bf(a.w) << 16);
    r.z = (unsigned)f2bf(b.x) | ((unsigned)f2bf(b.y) << 16);
    r.w = (unsigned)f2bf(b.z) | ((unsigned)f2bf(b.w) << 16);
    *(uint4*)(out + i) = r;
}

// ---------- fp32 [z][R][C] -> bf16 [z][C][R] tiled transpose ----------
__global__ __launch_bounds__(256)
void transpose_f2b(const float* __restrict__ in, unsigned short* __restrict__ out,
                   int R, int C, int tilesC, int ntile)
{
    int bid = blockIdx.x;
    int z = bid / ntile;
    int r = bid - z * ntile;
    int tr = r / tilesC, tc = r - tr * tilesC;
    const float* ib = in + (size_t)z * R * C;
    unsigned short* ob = out + (size_t)z * R * C;
    __shared__ float lds[32][33];
    int t = threadIdx.x;
    int i = t >> 3, j4 = (t & 7) << 2;
    float4 v = *(const float4*)(ib + (size_t)(tr * 32 + i) * C + tc * 32 + j4);
    lds[i][j4 + 0] = v.x;
    lds[i][j4 + 1] = v.y;
    lds[i][j4 + 2] = v.z;
    lds[i][j4 + 3] = v.w;
    __syncthreads();
    ushort4 o;
    o.x = f2bf(lds[j4 + 0][i]);
    o.y = f2bf(lds[j4 + 1][i]);
    o.z = f2bf(lds[j4 + 2][i]);
    o.w = f2bf(lds[j4 + 3][i]);
    *(ushort4*)(ob + (size_t)(tc * 32 + i) * R + tr * 32 + j4) = o;
}

// ---------------- fp32 SGEMM + bias + relu (gating L1/L2) ----------------
// C[M][N] = relu(A[M][K] @ B[K][N] + bias). Tile 64x64, 256 thr, 4x4/thr.
// 64x64 (not 128x128): L1 grid 1024 blocks (4/CU), L2 512 (2/CU) -- the
// 128x128 version ran at 1 block/CU (grid 256) and was latency-bound.
// Per-output k-accumulation order identical to before -> bit-identical
// gating logits -> identical routing.
__global__ __launch_bounds__(256)
void sgemm_relu(const float* __restrict__ A, const float* __restrict__ B,
                const float* __restrict__ bias, float* __restrict__ C,
                int N, int Kd, int nbn)
{
    int bid = blockIdx.x;
    int bm = bid / nbn, bn = bid - bm * nbn;
    __shared__ float As[16][64];   // [kk][row]
    __shared__ float Bs[16][64];   // [kk][col]
    int t = threadIdx.x;
    int tx = t & 15, ty = t >> 4;
    float acc[4][4];
#pragma unroll
    for (int i = 0; i < 4; ++i)
#pragma unroll
        for (int j = 0; j < 4; ++j) acc[i][j] = 0.f;

    int arow = t >> 2, akk = (t & 3) << 2;     // A: 64 rows x 16 k
    int bkk = t >> 4, bcol = (t & 15) << 2;    // B: 16 k x 64 cols
    const float* aptr = A + (size_t)(bm * 64 + arow) * Kd + akk;
    const float* bptr = B + (size_t)bkk * N + bn * 64 + bcol;

    for (int k0 = 0; k0 < Kd; k0 += 16) {
        float4 av = *(const float4*)(aptr + k0);
        float4 bv = *(const float4*)(bptr + (size_t)k0 * N);
        __syncthreads();
        As[akk + 0][arow] = av.x;
        As[akk + 1][arow] = av.y;
        As[akk + 2][arow] = av.z;
        As[akk + 3][arow] = av.w;
        *(float4*)&Bs[bkk][bcol] = bv;
        __syncthreads();
#pragma unroll
        for (int kk = 0; kk < 16; ++kk) {
            float a[4], b[4];
            *(float4*)&a[0] = *(const float4*)&As[kk][ty * 4];
            *(float4*)&b[0] = *(const float4*)&Bs[kk][tx * 4];
#pragma unroll
            for (int i = 0; i < 4; ++i)
#pragma unroll
                for (int j = 0; j < 4; ++j)
                    acc[i][j] = fmaf(a[i], b[j], acc[i][j]);
        }
    }
#pragma unroll
    for (int i = 0; i < 4; ++i) {
        int row = bm * 64 + ty * 4 + i;
        float4 o;
        float* op = &o.x;
#pragma unroll
        for (int j = 0; j < 4; ++j) {
            int col = bn * 64 + tx * 4 + j;
            float v = acc[i][j] + bias[col];
            op[j] = v > 0.f ? v : 0.f;
        }
        *(float4*)&C[(size_t)row * N + bn * 64 + tx * 4] = o;
    }
}

// ------------- gating L3 + type bias + softmax + top2 (per token) -------------
__global__ __launch_bounds__(256)
void gate_tail(const float* __restrict__ h2, const int* __restrict__ ftyp,
               const float* __restrict__ gw3, const float* __restrict__ gb3,
               const float* __restrict__ temb, const float* __restrict__ tw,
               const float* __restrict__ tb,
               int* __restrict__ eidx, float* __restrict__ ewt)
{
    __shared__ float sw3[GH2 * NEXP];
    __shared__ float stw[128 * NEXP];
    __shared__ float ste[3 * 128];
    int t = threadIdx.x;
    for (int i = t; i < GH2 * NEXP; i += 256) sw3[i] = gw3[i];
    for (int i = t; i < 128 * NEXP; i += 256) stw[i] = tw[i];
    for (int i = t; i < 3 * 128; i += 256) ste[i] = temb[i];
    __syncthreads();
    int tok = blockIdx.x * 256 + t;
    float lg[NEXP];
#pragma unroll
    for (int e = 0; e < NEXP; ++e) lg[e] = gb3[e] + tb[e];
    const float* hrow = h2 + (size_t)tok * GH2;
    for (int k = 0; k < GH2; k += 4) {
        float4 hv = *(const float4*)(hrow + k);
        float hvv[4] = {hv.x, hv.y, hv.z, hv.w};
#pragma unroll
        for (int j = 0; j < 4; ++j) {
            float v = hvv[j];
#pragma unroll
            for (int e = 0; e < NEXP; ++e)
                lg[e] = fmaf(v, sw3[(k + j) * NEXP + e], lg[e]);
        }
    }
    int ft = ftyp[tok];
    const float* te = ste + ft * 128;
    for (int k = 0; k < 128; k += 4) {
#pragma unroll
        for (int j = 0; j < 4; ++j) {
            float v = te[k + j];
#pragma unroll
            for (int e = 0; e < NEXP; ++e)
                lg[e] = fmaf(v, stw[(k + j) * NEXP + e], lg[e]);
        }
    }
    // top-2 on logits (softmax is monotone); ties -> lower index (matches lax.top_k)
    int a0 = 0; float b0 = lg[0];
#pragma unroll
    for (int e = 1; e < NEXP; ++e) if (lg[e] > b0) { b0 = lg[e]; a0 = e; }
    int a1 = -1; float b1 = -3.4e38f;
#pragma unroll
    for (int e = 0; e < NEXP; ++e) if (e != a0 && lg[e] > b1) { b1 = lg[e]; a1 = e; }
    // renormalized top-2 softmax weights == softmax over the two selected logits
    float w0 = 1.f / (1.f + expf(b1 - b0));
    eidx[tok * 2 + 0] = a0;
    eidx[tok * 2 + 1] = a1;
    ewt[tok * 2 + 0] = w0;
    ewt[tok * 2 + 1] = 1.f - w0;
}

// ---------------- routing: per-expert index lists ----------------
__global__ __launch_bounds__(256)
void route_kernel(const int* __restrict__ eidx, int* __restrict__ cnt,
                  int* __restrict__ entries)
{
    int tok = blockIdx.x * 256 + threadIdx.x;
#pragma unroll
    for (int k = 0; k < 2; ++k) {
        int e = eidx[tok * 2 + k];
        int p = atomicAdd(&cnt[e], 1);
        entries[e * T_TOK + p] = (tok << 1) | k;
    }
}

// ---------------- bf16 MFMA GEMM, 128x128 tile, BK=32 ----------------
// Double-buffered single-barrier K-loop (T3-minimum): stage(t+1)->buf^1
// overlaps ds_read+MFMA of buf[cur]; one __syncthreads() per iter supplies
// the vmcnt(0)+lgkmcnt(0)+barrier. Re-stage of a buffer is separated from
// its readers by exactly one barrier (reads complete before barrier since
// MFMA consumes them under compiler lgkmcnt).
// GATHER=1: expert GEMM, XCD-aligned (e = bid%8 -> all of expert e's blocks
// on XCD e; 4MB ewT panel fits 4MB XCD L2). GATHER=0: plain GEMM.
template<int GATHER>
__global__ __launch_bounds__(256)
void bgemm(const unsigned short* __restrict__ A, const unsigned short* __restrict__ BT,
           const float* __restrict__ bias, float* __restrict__ Cf,
           unsigned short* __restrict__ Y0, unsigned short* __restrict__ Y1,
           const int* __restrict__ entries, const int* __restrict__ cnt,
           int N, int Kd, int nbm, int nbn)
{
    int bid = blockIdx.x;
    int e = 0, bm, bn, cntE = 0;
    const unsigned short* Bt = BT;
    const float* bs = bias;
    if (GATHER) {
        e = bid & (NEXP - 1);          // expert == XCD (round-robin dispatch)
        int r = bid >> 3;              // [0, nbm*nbn)
        bm = r / nbn; bn = r - bm * nbn;
        cntE = cnt[e];
        if (bm * 128 >= cntE) return;
        Bt = BT + (size_t)e * HDIM * DDIM;
        bs = bias + e * HDIM;
    } else {
        bm = bid / nbn; bn = bid - bm * nbn;
    }

    __shared__ __align__(16) unsigned short As[2][128 * 32];
    __shared__ __align__(16) unsigned short Bs[2][128 * 32];
    __shared__ int rowtok[128];

    int t = threadIdx.x;
    if (GATHER) {
        if (t < 128) {
            int idx = bm * 128 + t;
            rowtok[t] = entries[(size_t)e * T_TOK + bm * 128 + ((idx < cntE) ? t : 0)];
        }
        __syncthreads();
    }

    int arow0 = t >> 2;
    int kkA = (t & 3) << 3;
    const unsigned short *asrc0, *asrc1;
    if (GATHER) {
        asrc0 = A + (size_t)(rowtok[arow0] >> 1) * Kd + kkA;
        asrc1 = A + (size_t)(rowtok[arow0 + 64] >> 1) * Kd + kkA;
    } else {
        asrc0 = A + (size_t)(bm * 128 + arow0) * Kd + kkA;
        asrc1 = A + (size_t)(bm * 128 + arow0 + 64) * Kd + kkA;
    }
    const unsigned short* bsrc0 = Bt + (size_t)(bn * 128 + arow0) * Kd + kkA;
    const unsigned short* bsrc1 = Bt + (size_t)(bn * 128 + arow0 + 64) * Kd + kkA;

    int lane = t & 63, wave = t >> 6;
    int wr = (wave >> 1) * 64, wc = (wave & 1) * 64;
    int l15 = lane & 15, lhi = lane >> 4;

    f32x4 zero = {0.f, 0.f, 0.f, 0.f};
    f32x4 acc[4][4];
#pragma unroll
    for (int m = 0; m < 4; ++m)
#pragma unroll
        for (int n = 0; n < 4; ++n) acc[m][n] = zero;

    // prologue: stage K-tile 0 into buffer 0
    async16(asrc0, &As[0][t * 8]);
    async16(asrc1, &As[0][t * 8 + 2048]);
    async16(bsrc0, &Bs[0][t * 8]);
    async16(bsrc1, &Bs[0][t * 8 + 2048]);
    __syncthreads();

    int nt = Kd >> 5;
    int cur = 0;
    for (int kt = 0; kt < nt; ++kt) {
        if (kt + 1 < nt) {             // issue next-tile loads into buf^1
            int k0 = (kt + 1) << 5;
            int nb = cur ^ 1;
            async16(asrc0 + k0, &As[nb][t * 8]);
            async16(asrc1 + k0, &As[nb][t * 8 + 2048]);
            async16(bsrc0 + k0, &Bs[nb][t * 8]);
            async16(bsrc1 + k0, &Bs[nb][t * 8 + 2048]);
        }
        short8 af[4], bf[4];
#pragma unroll
        for (int m = 0; m < 4; ++m)
            af[m] = *(const short8*)&As[cur][(wr + m * 16 + l15) * 32 + lhi * 8];
#pragma unroll
        for (int n = 0; n < 4; ++n)
            bf[n] = *(const short8*)&Bs[cur][(wc + n * 16 + l15) * 32 + lhi * 8];
#pragma unroll
        for (int m = 0; m < 4; ++m)
#pragma unroll
            for (int n = 0; n < 4; ++n)
                acc[m][n] = __builtin_amdgcn_mfma_f32_16x16x32_bf16(af[m], bf[n], acc[m][n], 0, 0, 0);
        __syncthreads();               // vmcnt(0)+lgkmcnt(0)+barrier
        cur ^= 1;
    }

    if (GATHER) {
#pragma unroll
        for (int m = 0; m < 4; ++m) {
            int rl = wr + m * 16 + lhi * 4;
#pragma unroll
            for (int q = 0; q < 4; ++q) {
                int gidx = bm * 128 + rl + q;
                if (gidx < cntE) {
                    int ent = rowtok[rl + q];
                    unsigned short* Y = (ent & 1) ? Y1 : Y0;
                    size_t rowoff = (size_t)(ent >> 1) * HDIM;
#pragma unroll
                    for (int n = 0; n < 4; ++n) {
                        int col = bn * 128 + wc + n * 16 + l15;
                        Y[rowoff + col] = f2bf(acc[m][n][q] + bs[col]);
                    }
                }
            }
        }
    } else {
#pragma unroll
        for (int m = 0; m < 4; ++m) {
            int row = bm * 128 + wr + m * 16 + lhi * 4;
#pragma unroll
            for (int n = 0; n < 4; ++n) {
                int col = bn * 128 + wc + n * 16 + l15;
                float bv = bs[col];
#pragma unroll
                for (int q = 0; q < 4; ++q)
                    Cf[(size_t)(row + q) * N + col] = acc[m][n][q] + bv;
            }
        }
    }
}

// ------------- combine: h = relu(w0*Y0 + w1*Y1) -> bf16 Hc -------------
__global__ __launch_bounds__(256)
void combine_kernel(const unsigned short* __restrict__ Y0,
                    const unsigned short* __restrict__ Y1,
                    const float* __restrict__ wts,
                    unsigned short* __restrict__ Hc)
{
    size_t i = (size_t)blockIdx.x * 256 + threadIdx.x;
    size_t base = i * 8;
    int tok = (int)(base >> 11);   // / HDIM
    float w0 = wts[tok * 2], w1 = wts[tok * 2 + 1];
    uint4 a = *(const uint4*)(Y0 + base);
    uint4 b = *(const uint4*)(Y1 + base);
    unsigned int ain[4] = {a.x, a.y, a.z, a.w};
    unsigned int bin[4] = {b.x, b.y, b.z, b.w};
    unsigned int r[4];
#pragma unroll
    for (int q = 0; q < 4; ++q) {
        float v0 = w0 * bf2f((unsigned short)(ain[q] & 0xffff)) +
                   w1 * bf2f((unsigned short)(bin[q] & 0xffff));
        float v1 = w0 * bf2f((unsigned short)(ain[q] >> 16)) +
                   w1 * bf2f((unsigned short)(bin[q] >> 16));
        v0 = v0 > 0.f ? v0 : 0.f;
        v1 = v1 > 0.f ? v1 : 0.f;
        r[q] = (unsigned int)f2bf(v0) | ((unsigned int)f2bf(v1) << 16);
    }
    uint4 o = {r[0], r[1], r[2], r[3]};
    *(uint4*)(Hc + base) = o;
}

// ------------------------------ launch ------------------------------
extern "C" void kernel_launch(void* const* d_in, const int* in_sizes, int n_in,
                              void* d_out, int out_size, void* d_ws, size_t ws_size,
                              hipStream_t stream)
{
    const float* x    = (const float*)d_in[0];
    const int*   ftyp = (const int*)d_in[1];
    const float* gw1  = (const float*)d_in[2];
    const float* gb1  = (const float*)d_in[3];
    const float* gw2  = (const float*)d_in[4];
    const float* gb2  = (const float*)d_in[5];
    const float* gw3  = (const float*)d_in[6];
    const float* gb3  = (const float*)d_in[7];
    const float* temb = (const float*)d_in[8];
    const float* tw   = (const float*)d_in[9];
    const float* tb   = (const float*)d_in[10];
    const float* ew   = (const float*)d_in[11];
    const float* eb   = (const float*)d_in[12];
    const float* ow   = (const float*)d_in[13];
    const float* ob   = (const float*)d_in[14];
    float* out = (float*)d_out;

    char* p = (char*)d_ws;
    auto alloc = [&](size_t bytes) {
        char* r = p;
        p += (bytes + 255) & ~(size_t)255;
        return r;
    };
    unsigned short* xb  = (unsigned short*)alloc((size_t)T_TOK * DDIM * 2);
    float* h1           = (float*)alloc((size_t)T_TOK * GH1 * 4);
    float* h2           = (float*)alloc((size_t)T_TOK * GH2 * 4);
    int* eidx           = (int*)alloc((size_t)T_TOK * 2 * 4);
    float* ewt          = (float*)alloc((size_t)T_TOK * 2 * 4);
    int* cnt            = (int*)alloc(256);
    int* entries        = (int*)alloc((size_t)NEXP * T_TOK * 4);
    unsigned short* ewT = (unsigned short*)alloc((size_t)NEXP * HDIM * DDIM * 2);
    unsigned short* owT = (unsigned short*)alloc((size_t)DDIM * HDIM * 2);
    unsigned short* Y0  = (unsigned short*)alloc((size_t)T_TOK * HDIM * 2);
    unsigned short* Y1  = (unsigned short*)alloc((size_t)T_TOK * HDIM * 2);
    unsigned short* Hc  = (unsigned short*)alloc((size_t)T_TOK * HDIM * 2);

    hipMemsetAsync(cnt, 0, 256, stream);
    f2b_kernel<<<(T_TOK * DDIM / 8) / 256, 256, 0, stream>>>(x, xb);
    // ew [8][1024][2048] -> ewT [8][2048][1024]
    transpose_f2b<<<NEXP * 32 * 64, 256, 0, stream>>>(ew, ewT, DDIM, HDIM, 64, 32 * 64);
    // ow [2048][1024] -> owT [1024][2048]
    transpose_f2b<<<64 * 32, 256, 0, stream>>>(ow, owT, HDIM, DDIM, 32, 64 * 32);

    sgemm_relu<<<128 * 8, 256, 0, stream>>>(x, gw1, gb1, h1, GH1, DDIM, 8);
    sgemm_relu<<<128 * 4, 256, 0, stream>>>(h1, gw2, gb2, h2, GH2, GH1, 4);
    gate_tail<<<T_TOK / 256, 256, 0, stream>>>(h2, ftyp, gw3, gb3, temb, tw, tb, eidx, ewt);
    route_kernel<<<T_TOK / 256, 256, 0, stream>>>(eidx, cnt, entries);

    bgemm<1><<<NEXP * 64 * 16, 256, 0, stream>>>(xb, ewT, eb, nullptr, Y0, Y1,
                                                 entries, cnt, HDIM, DDIM, 64, 16);
    combine_kernel<<<(T_TOK * HDIM / 8) / 256, 256, 0, stream>>>(Y0, Y1, ewt, Hc);
    bgemm<0><<<64 * 8, 256, 0, stream>>>(Hc, owT, ob, out, nullptr, nullptr,
                                         nullptr, nullptr, DDIM, HDIM, 64, 8);
}